// Round 2
// baseline (736.338 us; speedup 1.0000x reference)
//
#include <hip/hip_runtime.h>
#include <hip/hip_bf16.h>

#define B_ 4
#define S_ 2048
#define D_ 1024
#define H_ 16
#define M_ 8192   // B_*S_

typedef __attribute__((ext_vector_type(8))) _Float16 h8;
typedef __attribute__((ext_vector_type(4))) _Float16 h4;
typedef __attribute__((ext_vector_type(8))) short    s8;
typedef __attribute__((ext_vector_type(4))) float    f4;

#define AS1(p) ((const __attribute__((address_space(1))) void*)(p))
#define AS3(p) ((__attribute__((address_space(3))) void*)(p))

__device__ __forceinline__ f4 mfma16(h8 a, h8 b, f4 c) {
  return __builtin_amdgcn_mfma_f32_16x16x32_f16(a, b, c, 0, 0, 0);
}

// ---------------- cast f32 -> f16 (q,k,v,Wq,Wk,Wv,Wo) ----------------
struct CastArgs {
  const float* src[7];
  _Float16*    dst[7];
  int cum[8];   // cumulative 8-element chunk counts
};

__global__ __launch_bounds__(256) void cast_kernel(CastArgs a) {
  int idx = blockIdx.x * 256 + threadIdx.x;
  if (idx >= a.cum[7]) return;
  int seg = 0;
#pragma unroll
  for (int s = 1; s < 7; ++s) seg += (idx >= a.cum[s]) ? 1 : 0;
  size_t off = (size_t)(idx - a.cum[seg]) * 8;
  const float4* sp = (const float4*)(a.src[seg] + off);
  float4 u = sp[0], v = sp[1];
  union { _Float16 h[8]; h8 v8; } o;
  o.h[0] = (_Float16)u.x; o.h[1] = (_Float16)u.y;
  o.h[2] = (_Float16)u.z; o.h[3] = (_Float16)u.w;
  o.h[4] = (_Float16)v.x; o.h[5] = (_Float16)v.y;
  o.h[6] = (_Float16)v.z; o.h[7] = (_Float16)v.w;
  *(h8*)(a.dst[seg] + off) = o.v8;
}

// ---------------- bias precompute + transpose ----------------
// biasT[b][j(k-idx)][i(q-idx)] = mask[b][i][j] ? exp(-gamma*td[b][i][j]) : -30000
__global__ __launch_bounds__(256) void bias_kernel(
    const float* __restrict__ td, const int* __restrict__ mask,
    const float* __restrict__ gptr, _Float16* __restrict__ biasT)
{
  __shared__ _Float16 tile[64][66];       // pad: stride 66 shorts = 33 words -> conflict-free
  const float gamma = gptr[0];
  const int bid = blockIdx.x;
  const int b  = bid >> 10;
  const int i0 = ((bid >> 5) & 31) * 64;
  const int j0 = (bid & 31) * 64;
  const int t = threadIdx.x;
  const int c = t & 63, r0 = t >> 6;
#pragma unroll
  for (int it = 0; it < 16; ++it) {
    int r = r0 * 16 + it;
    size_t off = ((size_t)b * S_ + i0 + r) * S_ + j0 + c;
    float tv = td[off];
    int mk = mask[off];
    tile[r][c] = mk ? (_Float16)__expf(-gamma * tv) : (_Float16)(-30000.0f);
  }
  __syncthreads();
#pragma unroll
  for (int it = 0; it < 16; ++it) {
    int r = r0 * 16 + it;
    biasT[((size_t)b * S_ + j0 + r) * S_ + i0 + c] = tile[c][r];
  }
}

// ---------------- GEMM: C[M][1024] = (A[M][1024] @ Bt[1024][1024]^T + bias) * scale
template<bool F32OUT>
__global__ __launch_bounds__(256, 3) void gemm_bt(
    const _Float16* __restrict__ A,
    const _Float16* __restrict__ Bt,
    const float*    __restrict__ bias,
    void*           __restrict__ Cout,
    float scale)
{
  __shared__ __align__(16) _Float16 Alds[128 * 64];
  __shared__ __align__(16) _Float16 Blds[128 * 64];
  const int t = threadIdx.x;
  const int lane = t & 63, w = t >> 6;
  const int wm = w >> 1, wn = w & 1;
  const int m0 = blockIdx.x * 128, n0 = blockIdx.y * 128;
  const int ll = lane & 15, lg = lane >> 4;
  f4 acc[4][4] = {};

  for (int kt = 0; kt < 1024; kt += 64) {
    __syncthreads();
#pragma unroll
    for (int i = 0; i < 4; ++i) {
      int slot = i * 256 + t;
      int r = slot >> 3;
      int gs = ((slot & 7) ^ (r & 7)) * 8;
      __builtin_amdgcn_global_load_lds(AS1(A  + (size_t)(m0 + r) * 1024 + kt + gs),
                                       AS3((char*)Alds + (i * 256 + w * 64) * 16), 16, 0, 0);
      __builtin_amdgcn_global_load_lds(AS1(Bt + (size_t)(n0 + r) * 1024 + kt + gs),
                                       AS3((char*)Blds + (i * 256 + w * 64) * 16), 16, 0, 0);
    }
    __syncthreads();
#pragma unroll
    for (int ks = 0; ks < 2; ++ks) {
      h8 af[4], bf[4];
#pragma unroll
      for (int im = 0; im < 4; ++im) {
        int R = wm * 64 + im * 16 + ll;
        af[im] = *(const h8*)((const char*)Alds + R * 128 + (((ks * 4 + lg) ^ (R & 7)) << 4));
      }
#pragma unroll
      for (int in = 0; in < 4; ++in) {
        int R = wn * 64 + in * 16 + ll;
        bf[in] = *(const h8*)((const char*)Blds + R * 128 + (((ks * 4 + lg) ^ (R & 7)) << 4));
      }
#pragma unroll
      for (int im = 0; im < 4; ++im)
#pragma unroll
        for (int in = 0; in < 4; ++in)
          acc[im][in] = mfma16(af[im], bf[in], acc[im][in]);
    }
  }
#pragma unroll
  for (int im = 0; im < 4; ++im)
#pragma unroll
    for (int in = 0; in < 4; ++in) {
      int col = n0 + wn * 64 + in * 16 + ll;
      float bv = bias[col];
#pragma unroll
      for (int r = 0; r < 4; ++r) {
        int row = m0 + wm * 64 + im * 16 + lg * 4 + r;
        float vv = (acc[im][in][r] + bv) * scale;
        if constexpr (F32OUT) ((float*)Cout)[(size_t)row * 1024 + col] = vv;
        else ((_Float16*)Cout)[(size_t)row * 1024 + col] = (_Float16)vv;
      }
    }
}

// ---------------- V transpose: Vp[b*S+s][h*64+hd] -> Vt[(b*16+h)*64+hd][s] ----------------
__global__ __launch_bounds__(256) void transpose_v(
    const _Float16* __restrict__ Vp, _Float16* __restrict__ Vt)
{
  __shared__ __align__(16) short tile[64][72];
  const int blk = blockIdx.x;
  const int b = blk >> 9, h = (blk >> 5) & 15, st = blk & 31;
  const int s0 = st * 64, t = threadIdx.x;
#pragma unroll
  for (int it = 0; it < 2; ++it) {
    int slot = it * 256 + t;
    int r = slot >> 3, c = slot & 7;
    s8 v = *(const s8*)(Vp + (size_t)(b * S_ + s0 + r) * D_ + h * 64 + c * 8);
    *(s8*)&tile[r][c * 8] = v;
  }
  __syncthreads();
#pragma unroll
  for (int it = 0; it < 2; ++it) {
    int slot = it * 256 + t;
    int hd = slot >> 3, c = slot & 7;
    union { short hh[8]; s8 v8; } o;
#pragma unroll
    for (int e = 0; e < 8; ++e) o.hh[e] = tile[c * 8 + e][hd];
    *(s8*)(Vt + (size_t)((b * 16 + h) * 64 + hd) * S_ + s0 + c * 8) = o.v8;
  }
}

// ---------------- fused flash attention, barrier-free ----------------
// grid: 2048 blocks x 256 thr. block = (b, head, group of 4 q-tiles); wave w owns
// q-tile qg*4+w. All 4 waves share head -> identical K/V addresses (L1 broadcast).
// K prefetched 1 k-tile ahead (kA/kB ping-pong); V + bias issued early in body.

__device__ __forceinline__ void loadK(h8 (&dst)[8], const _Float16* Kb, int kt,
                                      int ll, int lg) {
#pragma unroll
  for (int jf = 0; jf < 4; ++jf) {
    const _Float16* kr = Kb + (size_t)(kt + jf * 16 + ll) * D_ + lg * 8;
    dst[2 * jf]     = *(const h8*)kr;
    dst[2 * jf + 1] = *(const h8*)(kr + 32);
  }
}

__device__ __forceinline__ void attn_body(
    int kt, const h8 (&kf)[8], h8 qf0, h8 qf1,
    const _Float16* __restrict__ Bb, const _Float16* __restrict__ Vb,
    char* pbase, int ll, int lg,
    float (&m)[4], float (&lsum)[4], f4 (&accO)[4])
{
  // S = QK^T  [q=lg*4+r][k=16jf+ll]
  f4 accS[4] = {};
#pragma unroll
  for (int jf = 0; jf < 4; ++jf) {
    accS[jf] = mfma16(qf0, kf[2 * jf],     accS[jf]);
    accS[jf] = mfma16(qf1, kf[2 * jf + 1], accS[jf]);
  }
  // bias loads (transposed layout -> 4 contiguous 8B loads)
  h4 bfr[4];
#pragma unroll
  for (int jf = 0; jf < 4; ++jf)
    bfr[jf] = *(const h4*)(Bb + (size_t)(kt + 16 * jf + ll) * S_);
  // V loads (consumed at end of body -> latency hidden under softmax)
  h8 vf[8];
#pragma unroll
  for (int ks = 0; ks < 2; ++ks)
#pragma unroll
    for (int df = 0; df < 4; ++df)
      vf[ks * 4 + df] = *(const h8*)(Vb + (size_t)(df * 16 + ll) * S_ + kt + ks * 32 + lg * 8);
  // + bias (masked = -30000 -> exp underflows to 0)
#pragma unroll
  for (int jf = 0; jf < 4; ++jf)
#pragma unroll
    for (int r = 0; r < 4; ++r)
      accS[jf][r] += (float)bfr[jf][r];

  // online softmax, rows i = lg*4+r, cols (jf, ll)
  float tm[4], esc[4], ts[4];
#pragma unroll
  for (int r = 0; r < 4; ++r)
    tm[r] = fmaxf(fmaxf(accS[0][r], accS[1][r]), fmaxf(accS[2][r], accS[3][r]));
#pragma unroll
  for (int d = 1; d < 16; d <<= 1)
#pragma unroll
    for (int r = 0; r < 4; ++r)
      tm[r] = fmaxf(tm[r], __shfl_xor(tm[r], d));
#pragma unroll
  for (int r = 0; r < 4; ++r) {
    float mn = fmaxf(m[r], tm[r]);
    esc[r] = __expf(m[r] - mn);
    m[r] = mn;
    ts[r] = 0.f;
  }
#pragma unroll
  for (int jf = 0; jf < 4; ++jf)
#pragma unroll
    for (int r = 0; r < 4; ++r) {
      float p = __expf(accS[jf][r] - m[r]);
      ts[r] += p;
      int i = lg * 4 + r, j = ll + 16 * jf;
      *(_Float16*)(pbase + i * 128 + ((2 * j) ^ ((i & 7) << 4))) = (_Float16)p;
    }
#pragma unroll
  for (int d = 1; d < 16; d <<= 1)
#pragma unroll
    for (int r = 0; r < 4; ++r)
      ts[r] += __shfl_xor(ts[r], d);
#pragma unroll
  for (int r = 0; r < 4; ++r)
    lsum[r] = lsum[r] * esc[r] + ts[r];

  // rescale accO: need esc for row = ll (cross-lane move, in-register)
  float es = esc[0];
  es = ((ll & 3) == 1) ? esc[1] : es;
  es = ((ll & 3) == 2) ? esc[2] : es;
  es = ((ll & 3) == 3) ? esc[3] : es;
  float ef = __shfl(es, ((ll >> 2) << 4) + ll);
#pragma unroll
  for (int df = 0; df < 4; ++df)
#pragma unroll
    for (int r = 0; r < 4; ++r)
      accO[df][r] *= ef;

  // O^T += V^T . P^T
#pragma unroll
  for (int ks = 0; ks < 2; ++ks) {
    h8 pf = *(const h8*)(pbase + ll * 128 + ((ks * 64 + lg * 16) ^ ((ll & 7) << 4)));
#pragma unroll
    for (int df = 0; df < 4; ++df)
      accO[df] = mfma16(vf[ks * 4 + df], pf, accO[df]);
  }
}

__global__ __launch_bounds__(256, 3) void attn_kernel(
    const _Float16* __restrict__ Qp,    // [8192][1024], pre-scaled by 1/8
    const _Float16* __restrict__ Kp,    // [8192][1024]
    const _Float16* __restrict__ Vt,    // [(b*16+h)*64+hd][2048]
    const _Float16* __restrict__ biasT, // [4][2048(k)][2048(q)]
    _Float16*       __restrict__ Oa)    // [8192][1024]
{
  __shared__ __align__(16) short P_lds[4][16 * 64];   // per-wave, XOR-swizzled
  const int t = threadIdx.x;
  const int lane = t & 63, w = t >> 6;
  const int ll = lane & 15, lg = lane >> 4;
  const int bid = blockIdx.x;
  const int b  = bid >> 9;
  const int h  = (bid >> 5) & 15;
  const int qg = bid & 31;
  const int q0 = (qg * 4 + w) * 16;

  const _Float16* Kb = Kp + (size_t)b * S_ * D_ + h * 64;
  const _Float16* Vb = Vt + (size_t)(b * 16 + h) * 64 * S_;
  const _Float16* Bb = biasT + (size_t)b * S_ * S_ + q0 + lg * 4;
  char* pbase = (char*)&P_lds[w][0];

  const size_t qrow = (size_t)(b * S_ + q0 + ll) * D_ + h * 64;
  h8 qf0 = *(const h8*)(Qp + qrow + lg * 8);
  h8 qf1 = *(const h8*)(Qp + qrow + 32 + lg * 8);

  float m[4], lsum[4];
#pragma unroll
  for (int r = 0; r < 4; ++r) { m[r] = -1e30f; lsum[r] = 0.f; }
  f4 accO[4] = {};

  h8 kA[8], kB[8];
  loadK(kA, Kb, 0, ll, lg);

  for (int kt = 0; kt < S_; kt += 128) {
    loadK(kB, Kb, kt + 64, ll, lg);
    attn_body(kt, kA, qf0, qf1, Bb, Vb, pbase, ll, lg, m, lsum, accO);
    if (kt + 128 < S_) loadK(kA, Kb, kt + 128, ll, lg);
    attn_body(kt + 64, kB, qf0, qf1, Bb, Vb, pbase, ll, lg, m, lsum, accO);
  }

  // finalize: 1/rowsum for row = ll via the same cross-lane move
  float ls = lsum[0];
  ls = ((ll & 3) == 1) ? lsum[1] : ls;
  ls = ((ll & 3) == 2) ? lsum[2] : ls;
  ls = ((ll & 3) == 3) ? lsum[3] : ls;
  float lf = __shfl(ls, ((ll >> 2) << 4) + ll);
  float linv = 1.0f / lf;
#pragma unroll
  for (int df = 0; df < 4; ++df)
#pragma unroll
    for (int r = 0; r < 4; ++r) {
      size_t orow = (size_t)(b * S_ + q0 + ll) * D_ + h * 64 + df * 16 + lg * 4 + r;
      Oa[orow] = (_Float16)(accO[df][r] * linv);
    }
}

// ---------------- launcher ----------------
extern "C" void kernel_launch(void* const* d_in, const int* in_sizes, int n_in,
                              void* d_out, int out_size, void* d_ws, size_t ws_size,
                              hipStream_t stream) {
  const float* q    = (const float*)d_in[0];
  const float* k    = (const float*)d_in[1];
  const float* v    = (const float*)d_in[2];
  const float* td   = (const float*)d_in[3];
  const int*   mask = (const int*)d_in[4];
  const float* Wq   = (const float*)d_in[5];
  const float* bq   = (const float*)d_in[6];
  const float* Wk   = (const float*)d_in[7];
  const float* bk   = (const float*)d_in[8];
  const float* Wv   = (const float*)d_in[9];
  const float* bv   = (const float*)d_in[10];
  const float* Wo   = (const float*)d_in[11];
  const float* bo   = (const float*)d_in[12];
  const float* gm   = (const float*)d_in[13];

  const size_t MD = (size_t)M_ * D_;      // 8388608
  const size_t WW = (size_t)D_ * D_;      // 1048576
  if (ws_size < (8 * MD + 4 * WW) * sizeof(_Float16)) return;

  _Float16* base = (_Float16*)d_ws;
  _Float16* qh = base;
  _Float16* kh = qh + MD;
  _Float16* vh = kh + MD;
  _Float16* wq = vh + MD;
  _Float16* wk = wq + WW;
  _Float16* wv = wk + WW;
  _Float16* wo = wv + WW;
  _Float16* Qp = wo + WW;
  _Float16* Kp = Qp + MD;
  _Float16* Vp = Kp + MD;
  _Float16* Vt = Vp + MD;
  _Float16* Oa = Vt + MD;
  _Float16* biasT = qh;   // reuse qh+kh (2*MD = B*S*S) after gemmQ/gemmK consume them

  CastArgs ca;
  ca.src[0] = q;  ca.src[1] = k;  ca.src[2] = v;
  ca.src[3] = Wq; ca.src[4] = Wk; ca.src[5] = Wv; ca.src[6] = Wo;
  ca.dst[0] = qh; ca.dst[1] = kh; ca.dst[2] = vh;
  ca.dst[3] = wq; ca.dst[4] = wk; ca.dst[5] = wv; ca.dst[6] = wo;
  int sizes[7] = {(int)(MD / 8), (int)(MD / 8), (int)(MD / 8),
                  (int)(WW / 8), (int)(WW / 8), (int)(WW / 8), (int)(WW / 8)};
  int c = 0; ca.cum[0] = 0;
  for (int i = 0; i < 7; ++i) { c += sizes[i]; ca.cum[i + 1] = c; }
  cast_kernel<<<(c + 255) / 256, 256, 0, stream>>>(ca);

  dim3 gg(64, 8);
  gemm_bt<false><<<gg, 256, 0, stream>>>(qh, wq, bq, Qp, 0.125f);  // 1/sqrt(HD) folded in
  gemm_bt<false><<<gg, 256, 0, stream>>>(kh, wk, bk, Kp, 1.0f);
  bias_kernel<<<4096, 256, 0, stream>>>(td, mask, gm, biasT);      // overwrites qh/kh
  gemm_bt<false><<<gg, 256, 0, stream>>>(vh, wv, bv, Vp, 1.0f);
  transpose_v<<<2048, 256, 0, stream>>>(Vp, Vt);
  attn_kernel<<<2048, 256, 0, stream>>>(Qp, Kp, Vt, biasT, Oa);
  gemm_bt<true><<<gg, 256, 0, stream>>>(Oa, wo, bo, d_out, 1.0f);
}

// Round 3
// 435.750 us; speedup vs baseline: 1.6898x; 1.6898x over previous
//
#include <hip/hip_runtime.h>
#include <hip/hip_bf16.h>

#define B_ 4
#define S_ 2048
#define D_ 1024
#define H_ 16
#define M_ 8192   // B_*S_

typedef __attribute__((ext_vector_type(8))) _Float16 h8;
typedef __attribute__((ext_vector_type(4))) _Float16 h4;
typedef __attribute__((ext_vector_type(8))) short    s8;
typedef __attribute__((ext_vector_type(4))) float    f4;

#define AS1(p) ((const __attribute__((address_space(1))) void*)(p))
#define AS3(p) ((__attribute__((address_space(3))) void*)(p))

__device__ __forceinline__ f4 mfma16(h8 a, h8 b, f4 c) {
  return __builtin_amdgcn_mfma_f32_16x16x32_f16(a, b, c, 0, 0, 0);
}

// ---------------- cast f32 -> f16 (q,k,v,Wq,Wk,Wv,Wo) ----------------
struct CastArgs {
  const float* src[7];
  _Float16*    dst[7];
  int cum[8];
};

__global__ __launch_bounds__(256) void cast_kernel(CastArgs a) {
  int idx = blockIdx.x * 256 + threadIdx.x;
  if (idx >= a.cum[7]) return;
  int seg = 0;
#pragma unroll
  for (int s = 1; s < 7; ++s) seg += (idx >= a.cum[s]) ? 1 : 0;
  size_t off = (size_t)(idx - a.cum[seg]) * 8;
  const float4* sp = (const float4*)(a.src[seg] + off);
  float4 u = sp[0], v = sp[1];
  union { _Float16 h[8]; h8 v8; } o;
  o.h[0] = (_Float16)u.x; o.h[1] = (_Float16)u.y;
  o.h[2] = (_Float16)u.z; o.h[3] = (_Float16)u.w;
  o.h[4] = (_Float16)v.x; o.h[5] = (_Float16)v.y;
  o.h[6] = (_Float16)v.z; o.h[7] = (_Float16)v.w;
  *(h8*)(a.dst[seg] + off) = o.v8;
}

// ---------------- bias precompute + transpose ----------------
// biasT[b][j(k-idx)][i(q-idx)] = mask[b][i][j] ? exp(-gamma*td[b][i][j]) : -30000
__global__ __launch_bounds__(256) void bias_kernel(
    const float* __restrict__ td, const int* __restrict__ mask,
    const float* __restrict__ gptr, _Float16* __restrict__ biasT)
{
  __shared__ _Float16 tile[64][66];
  const float gamma = gptr[0];
  const int bid = blockIdx.x;
  const int b  = bid >> 10;
  const int i0 = ((bid >> 5) & 31) * 64;
  const int j0 = (bid & 31) * 64;
  const int t = threadIdx.x;
  const int c = t & 63, r0 = t >> 6;
#pragma unroll
  for (int it = 0; it < 16; ++it) {
    int r = r0 * 16 + it;
    size_t off = ((size_t)b * S_ + i0 + r) * S_ + j0 + c;
    float tv = td[off];
    int mk = mask[off];
    tile[r][c] = mk ? (_Float16)__expf(-gamma * tv) : (_Float16)(-30000.0f);
  }
  __syncthreads();
#pragma unroll
  for (int it = 0; it < 16; ++it) {
    int r = r0 * 16 + it;
    biasT[((size_t)b * S_ + j0 + r) * S_ + i0 + c] = tile[c][r];
  }
}

// ---------------- GEMM: C[M][1024] = (A[M][1024] @ Bt[1024][1024]^T + bias) * scale
template<bool F32OUT>
__global__ __launch_bounds__(256, 3) void gemm_bt(
    const _Float16* __restrict__ A,
    const _Float16* __restrict__ Bt,
    const float*    __restrict__ bias,
    void*           __restrict__ Cout,
    float scale)
{
  __shared__ __align__(16) _Float16 Alds[128 * 64];
  __shared__ __align__(16) _Float16 Blds[128 * 64];
  const int t = threadIdx.x;
  const int lane = t & 63, w = t >> 6;
  const int wm = w >> 1, wn = w & 1;
  const int m0 = blockIdx.x * 128, n0 = blockIdx.y * 128;
  const int ll = lane & 15, lg = lane >> 4;
  f4 acc[4][4] = {};

  for (int kt = 0; kt < 1024; kt += 64) {
    __syncthreads();
#pragma unroll
    for (int i = 0; i < 4; ++i) {
      int slot = i * 256 + t;
      int r = slot >> 3;
      int gs = ((slot & 7) ^ (r & 7)) * 8;
      __builtin_amdgcn_global_load_lds(AS1(A  + (size_t)(m0 + r) * 1024 + kt + gs),
                                       AS3((char*)Alds + (i * 256 + w * 64) * 16), 16, 0, 0);
      __builtin_amdgcn_global_load_lds(AS1(Bt + (size_t)(n0 + r) * 1024 + kt + gs),
                                       AS3((char*)Blds + (i * 256 + w * 64) * 16), 16, 0, 0);
    }
    __syncthreads();
#pragma unroll
    for (int ks = 0; ks < 2; ++ks) {
      h8 af[4], bf[4];
#pragma unroll
      for (int im = 0; im < 4; ++im) {
        int R = wm * 64 + im * 16 + ll;
        af[im] = *(const h8*)((const char*)Alds + R * 128 + (((ks * 4 + lg) ^ (R & 7)) << 4));
      }
#pragma unroll
      for (int in = 0; in < 4; ++in) {
        int R = wn * 64 + in * 16 + ll;
        bf[in] = *(const h8*)((const char*)Blds + R * 128 + (((ks * 4 + lg) ^ (R & 7)) << 4));
      }
#pragma unroll
      for (int im = 0; im < 4; ++im)
#pragma unroll
        for (int in = 0; in < 4; ++in)
          acc[im][in] = mfma16(af[im], bf[in], acc[im][in]);
    }
  }
#pragma unroll
  for (int im = 0; im < 4; ++im)
#pragma unroll
    for (int in = 0; in < 4; ++in) {
      int col = n0 + wn * 64 + in * 16 + ll;
      float bv = bias[col];
#pragma unroll
      for (int r = 0; r < 4; ++r) {
        int row = m0 + wm * 64 + im * 16 + lg * 4 + r;
        float vv = (acc[im][in][r] + bv) * scale;
        if constexpr (F32OUT) ((float*)Cout)[(size_t)row * 1024 + col] = vv;
        else ((_Float16*)Cout)[(size_t)row * 1024 + col] = (_Float16)vv;
      }
    }
}

// ---------------- V transpose: Vp[b*S+s][h*64+hd] -> Vt[(b*16+h)*64+hd][s] ----------------
__global__ __launch_bounds__(256) void transpose_v(
    const _Float16* __restrict__ Vp, _Float16* __restrict__ Vt)
{
  __shared__ __align__(16) short tile[64][72];
  const int blk = blockIdx.x;
  const int b = blk >> 9, h = (blk >> 5) & 15, st = blk & 31;
  const int s0 = st * 64, t = threadIdx.x;
#pragma unroll
  for (int it = 0; it < 2; ++it) {
    int slot = it * 256 + t;
    int r = slot >> 3, c = slot & 7;
    s8 v = *(const s8*)(Vp + (size_t)(b * S_ + s0 + r) * D_ + h * 64 + c * 8);
    *(s8*)&tile[r][c * 8] = v;
  }
  __syncthreads();
#pragma unroll
  for (int it = 0; it < 2; ++it) {
    int slot = it * 256 + t;
    int hd = slot >> 3, c = slot & 7;
    union { short hh[8]; s8 v8; } o;
#pragma unroll
    for (int e = 0; e < 8; ++e) o.hh[e] = tile[c * 8 + e][hd];
    *(s8*)(Vt + (size_t)((b * 16 + h) * 64 + hd) * S_ + s0 + c * 8) = o.v8;
  }
}

// ---------------- fused flash attention, LDS-staged + counted-vmcnt pipeline ----
// Block = (b, h, 64 q-rows), 4 waves x 16 q-rows. Per 64-k-tile: K/V^T/bias tiles
// staged coalesced into double-buffered LDS via global_load_lds (24 x 1KB instrs,
// 6 per wave), stage(t+1) in flight across barriers with s_waitcnt vmcnt(6).
// LDS: K 2x8K | V 2x8K | bias 2x8K | P 4x2K = 56KB -> 2 blocks/CU.
#define KL_OFF   0
#define VL_OFF   16384
#define BL_OFF   32768
#define PL_OFF   49152

__global__ __launch_bounds__(256, 2) void attn_kernel(
    const _Float16* __restrict__ Qp,    // [8192][1024], pre-scaled by 1/8
    const _Float16* __restrict__ Kp,    // [8192][1024]
    const _Float16* __restrict__ Vt,    // [(b*16+h)*64+hd][2048]
    const _Float16* __restrict__ biasT, // [4][2048(k)][2048(q)]
    _Float16*       __restrict__ Oa)    // [8192][1024]
{
  __shared__ __align__(16) char lds[57344];
  const int t = threadIdx.x;
  const int lane = t & 63, w = t >> 6;
  const int ll = lane & 15, lg = lane >> 4;
  const int bid = blockIdx.x;
  const int b  = bid >> 9;
  const int h  = (bid >> 5) & 15;
  const int qg = bid & 31;
  const int q0b = qg * 64;            // block q base
  const int q0  = q0b + w * 16;       // wave q base

  // per-lane staging offsets: row-in-group + XOR-swizzled chunk
  const int lrow = lane >> 3;
  const int lcs  = (lane & 7) ^ lrow;

  const _Float16* Kg = Kp + (size_t)b * S_ * D_ + h * 64;
  const _Float16* Vg = Vt + (size_t)(b * 16 + h) * 64 * S_;
  const _Float16* Bg = biasT + (size_t)b * S_ * S_ + q0b;

  char* pbase = lds + PL_OFF + w * 2048;

  // Q a-frags hoisted (pre-scaled by 1/8 in projection)
  const size_t qrow = (size_t)(b * S_ + q0 + ll) * D_ + h * 64;
  h8 qf0 = *(const h8*)(Qp + qrow + lg * 8);
  h8 qf1 = *(const h8*)(Qp + qrow + 32 + lg * 8);

  float m[4], lsum[4];
#pragma unroll
  for (int r = 0; r < 4; ++r) { m[r] = -1e30f; lsum[r] = 0.f; }
  f4 accO[4] = {};

  // stage one 64-k tile (6 gload_lds per wave: wave w owns instrs w*6..w*6+5)
  auto STAGE = [&](int kt, int bufb) {
#pragma unroll
    for (int j = 0; j < 6; ++j) {
      int i = w * 6 + j;            // 0..23
      int g = i & 7;                // group of 8 rows
      int row8 = g * 8 + lrow;
      const _Float16* src;
      char* dst;
      if (i < 8) {
        src = Kg + (size_t)(kt + row8) * D_ + lcs * 8;
        dst = lds + KL_OFF + bufb * 8192 + g * 1024;
      } else if (i < 16) {
        src = Vg + (size_t)row8 * S_ + kt + lcs * 8;
        dst = lds + VL_OFF + bufb * 8192 + g * 1024;
      } else {
        src = Bg + (size_t)(kt + row8) * S_ + lcs * 8;
        dst = lds + BL_OFF + bufb * 8192 + g * 1024;
      }
      __builtin_amdgcn_global_load_lds(AS1(src), AS3(dst), 16, 0, 0);
    }
  };

  // prologue
  STAGE(0, 0);
  asm volatile("s_waitcnt vmcnt(0)" ::: "memory");
  __builtin_amdgcn_sched_barrier(0);
  __builtin_amdgcn_s_barrier();
  __builtin_amdgcn_sched_barrier(0);

  for (int tt = 0; tt < 32; ++tt) {
    const int bufb = tt & 1;
    const int kt = tt * 64;
    if (tt < 31) {
      STAGE(kt + 64, bufb ^ 1);
      asm volatile("s_waitcnt vmcnt(6)" ::: "memory");
    } else {
      asm volatile("s_waitcnt vmcnt(0)" ::: "memory");
    }
    __builtin_amdgcn_sched_barrier(0);
    __builtin_amdgcn_s_barrier();     // tile tt ready in buf[bufb] for all waves
    __builtin_amdgcn_sched_barrier(0);

    const char* Kb = lds + KL_OFF + bufb * 8192;
    const char* Vb = lds + VL_OFF + bufb * 8192;
    const char* Bb = lds + BL_OFF + bufb * 8192;

    // S = QK^T  [q=lg*4+r][k=16jf+ll]
    f4 accS[4] = {};
#pragma unroll
    for (int jf = 0; jf < 4; ++jf) {
      int row = jf * 16 + ll;
      h8 k0 = *(const h8*)(Kb + row * 128 + (((lg)     ^ (row & 7)) << 4));
      h8 k1 = *(const h8*)(Kb + row * 128 + (((4 + lg) ^ (row & 7)) << 4));
      accS[jf] = mfma16(qf0, k0, accS[jf]);
      accS[jf] = mfma16(qf1, k1, accS[jf]);
    }
    // + bias (masked = -30000 -> exp underflows to 0)
#pragma unroll
    for (int jf = 0; jf < 4; ++jf) {
      int row = jf * 16 + ll;
      int c16 = w * 2 + (lg >> 1);
      h4 bv = *(const h4*)(Bb + row * 128 + ((c16 ^ (row & 7)) << 4) + (lg & 1) * 8);
#pragma unroll
      for (int r = 0; r < 4; ++r)
        accS[jf][r] += (float)bv[r];
    }

    // online softmax, rows i = lg*4+r, cols (jf, ll)
    float tm[4], esc[4], ts[4];
#pragma unroll
    for (int r = 0; r < 4; ++r)
      tm[r] = fmaxf(fmaxf(accS[0][r], accS[1][r]), fmaxf(accS[2][r], accS[3][r]));
#pragma unroll
    for (int d = 1; d < 16; d <<= 1)
#pragma unroll
      for (int r = 0; r < 4; ++r)
        tm[r] = fmaxf(tm[r], __shfl_xor(tm[r], d));
#pragma unroll
    for (int r = 0; r < 4; ++r) {
      float mn = fmaxf(m[r], tm[r]);
      esc[r] = __expf(m[r] - mn);
      m[r] = mn;
      ts[r] = 0.f;
    }
#pragma unroll
    for (int jf = 0; jf < 4; ++jf)
#pragma unroll
      for (int r = 0; r < 4; ++r) {
        float p = __expf(accS[jf][r] - m[r]);
        ts[r] += p;
        int i = lg * 4 + r, j = ll + 16 * jf;
        *(_Float16*)(pbase + i * 128 + ((2 * j) ^ ((i & 7) << 4))) = (_Float16)p;
      }
#pragma unroll
    for (int d = 1; d < 16; d <<= 1)
#pragma unroll
      for (int r = 0; r < 4; ++r)
        ts[r] += __shfl_xor(ts[r], d);
#pragma unroll
    for (int r = 0; r < 4; ++r)
      lsum[r] = lsum[r] * esc[r] + ts[r];

    // rescale accO: esc for row = ll via in-register cross-lane move
    float es = esc[0];
    es = ((ll & 3) == 1) ? esc[1] : es;
    es = ((ll & 3) == 2) ? esc[2] : es;
    es = ((ll & 3) == 3) ? esc[3] : es;
    float ef = __shfl(es, ((ll >> 2) << 4) + ll);
#pragma unroll
    for (int df = 0; df < 4; ++df)
#pragma unroll
      for (int r = 0; r < 4; ++r)
        accO[df][r] *= ef;

    // O^T += V^T . P^T
#pragma unroll
    for (int ks = 0; ks < 2; ++ks) {
      h8 pf = *(const h8*)(pbase + ll * 128 + ((ks * 64 + lg * 16) ^ ((ll & 7) << 4)));
#pragma unroll
      for (int df = 0; df < 4; ++df) {
        int vrow = df * 16 + ll;
        h8 vfr = *(const h8*)(Vb + vrow * 128 + (((ks * 4 + lg) ^ (vrow & 7)) << 4));
        accO[df] = mfma16(vfr, pf, accO[df]);
      }
    }

    __builtin_amdgcn_sched_barrier(0);
    __builtin_amdgcn_s_barrier();     // all waves done reading buf[bufb]
    __builtin_amdgcn_sched_barrier(0);
  }

  // finalize: 1/rowsum for row = ll via the same cross-lane move
  float ls = lsum[0];
  ls = ((ll & 3) == 1) ? lsum[1] : ls;
  ls = ((ll & 3) == 2) ? lsum[2] : ls;
  ls = ((ll & 3) == 3) ? lsum[3] : ls;
  float lf = __shfl(ls, ((ll >> 2) << 4) + ll);
  float linv = 1.0f / lf;
#pragma unroll
  for (int df = 0; df < 4; ++df)
#pragma unroll
    for (int r = 0; r < 4; ++r) {
      size_t orow = (size_t)(b * S_ + q0 + ll) * D_ + h * 64 + df * 16 + lg * 4 + r;
      Oa[orow] = (_Float16)(accO[df][r] * linv);
    }
}

// ---------------- launcher ----------------
extern "C" void kernel_launch(void* const* d_in, const int* in_sizes, int n_in,
                              void* d_out, int out_size, void* d_ws, size_t ws_size,
                              hipStream_t stream) {
  const float* q    = (const float*)d_in[0];
  const float* k    = (const float*)d_in[1];
  const float* v    = (const float*)d_in[2];
  const float* td   = (const float*)d_in[3];
  const int*   mask = (const int*)d_in[4];
  const float* Wq   = (const float*)d_in[5];
  const float* bq   = (const float*)d_in[6];
  const float* Wk   = (const float*)d_in[7];
  const float* bk   = (const float*)d_in[8];
  const float* Wv   = (const float*)d_in[9];
  const float* bv   = (const float*)d_in[10];
  const float* Wo   = (const float*)d_in[11];
  const float* bo   = (const float*)d_in[12];
  const float* gm   = (const float*)d_in[13];

  const size_t MD = (size_t)M_ * D_;      // 8388608
  const size_t WW = (size_t)D_ * D_;      // 1048576
  if (ws_size < (8 * MD + 4 * WW) * sizeof(_Float16)) return;

  _Float16* base = (_Float16*)d_ws;
  _Float16* qh = base;
  _Float16* kh = qh + MD;
  _Float16* vh = kh + MD;
  _Float16* wq = vh + MD;
  _Float16* wk = wq + WW;
  _Float16* wv = wk + WW;
  _Float16* wo = wv + WW;
  _Float16* Qp = wo + WW;
  _Float16* Kp = Qp + MD;
  _Float16* Vp = Kp + MD;
  _Float16* Vt = Vp + MD;
  _Float16* Oa = Vt + MD;
  _Float16* biasT = qh;   // reuse qh+kh (2*MD = B*S*S) after gemmQ/gemmK consume them

  CastArgs ca;
  ca.src[0] = q;  ca.src[1] = k;  ca.src[2] = v;
  ca.src[3] = Wq; ca.src[4] = Wk; ca.src[5] = Wv; ca.src[6] = Wo;
  ca.dst[0] = qh; ca.dst[1] = kh; ca.dst[2] = vh;
  ca.dst[3] = wq; ca.dst[4] = wk; ca.dst[5] = wv; ca.dst[6] = wo;
  int sizes[7] = {(int)(MD / 8), (int)(MD / 8), (int)(MD / 8),
                  (int)(WW / 8), (int)(WW / 8), (int)(WW / 8), (int)(WW / 8)};
  int c = 0; ca.cum[0] = 0;
  for (int i = 0; i < 7; ++i) { c += sizes[i]; ca.cum[i + 1] = c; }
  cast_kernel<<<(c + 255) / 256, 256, 0, stream>>>(ca);

  dim3 gg(64, 8);
  gemm_bt<false><<<gg, 256, 0, stream>>>(qh, wq, bq, Qp, 0.125f);  // 1/sqrt(HD) folded in
  gemm_bt<false><<<gg, 256, 0, stream>>>(kh, wk, bk, Kp, 1.0f);
  bias_kernel<<<4096, 256, 0, stream>>>(td, mask, gm, biasT);      // overwrites qh/kh
  gemm_bt<false><<<gg, 256, 0, stream>>>(vh, wv, bv, Vp, 1.0f);
  transpose_v<<<2048, 256, 0, stream>>>(Vp, Vt);
  attn_kernel<<<2048, 256, 0, stream>>>(Qp, Kp, Vt, biasT, Oa);
  gemm_bt<true><<<gg, 256, 0, stream>>>(Oa, wo, bo, d_out, 1.0f);
}

// Round 4
// 348.831 us; speedup vs baseline: 2.1109x; 1.2492x over previous
//
#include <hip/hip_runtime.h>
#include <hip/hip_bf16.h>

#define B_ 4
#define S_ 2048
#define D_ 1024
#define H_ 16
#define M_ 8192   // B_*S_

typedef __attribute__((ext_vector_type(8))) _Float16 h8;
typedef __attribute__((ext_vector_type(4))) _Float16 h4;
typedef __attribute__((ext_vector_type(8))) short    s8;
typedef __attribute__((ext_vector_type(4))) float    f4;

#define AS1(p) ((const __attribute__((address_space(1))) void*)(p))
#define AS3(p) ((__attribute__((address_space(3))) void*)(p))

__device__ __forceinline__ f4 mfma16(h8 a, h8 b, f4 c) {
  return __builtin_amdgcn_mfma_f32_16x16x32_f16(a, b, c, 0, 0, 0);
}

// ---------------- cast f32 -> f16 (q,k,v,Wq,Wk,Wv,Wo) ----------------
struct CastArgs {
  const float* src[7];
  _Float16*    dst[7];
  int cum[8];
};

__global__ __launch_bounds__(256) void cast_kernel(CastArgs a) {
  int idx = blockIdx.x * 256 + threadIdx.x;
  if (idx >= a.cum[7]) return;
  int seg = 0;
#pragma unroll
  for (int s = 1; s < 7; ++s) seg += (idx >= a.cum[s]) ? 1 : 0;
  size_t off = (size_t)(idx - a.cum[seg]) * 8;
  const float4* sp = (const float4*)(a.src[seg] + off);
  float4 u = sp[0], v = sp[1];
  union { _Float16 h[8]; h8 v8; } o;
  o.h[0] = (_Float16)u.x; o.h[1] = (_Float16)u.y;
  o.h[2] = (_Float16)u.z; o.h[3] = (_Float16)u.w;
  o.h[4] = (_Float16)v.x; o.h[5] = (_Float16)v.y;
  o.h[6] = (_Float16)v.z; o.h[7] = (_Float16)v.w;
  *(h8*)(a.dst[seg] + off) = o.v8;
}

// ---------------- bias precompute + transpose ----------------
// biasT[b][j(k)][i(q)] = mask ? exp(-gamma*td)/ln2 : -30000   (f16)
// The 1/ln2 factor folds softmax's exp into a single v_exp_f32 (2^x).
__global__ __launch_bounds__(256) void bias_kernel(
    const float* __restrict__ td, const int* __restrict__ mask,
    const float* __restrict__ gptr, _Float16* __restrict__ biasT)
{
  __shared__ _Float16 tile[64][66];
  const float gamma = gptr[0];
  const int bid = blockIdx.x;
  const int b  = bid >> 10;
  const int i0 = ((bid >> 5) & 31) * 64;
  const int j0 = (bid & 31) * 64;
  const int t = threadIdx.x;
  const int c = t & 63, r0 = t >> 6;
#pragma unroll
  for (int it = 0; it < 16; ++it) {
    int r = r0 * 16 + it;
    size_t off = ((size_t)b * S_ + i0 + r) * S_ + j0 + c;
    float tv = td[off];
    int mk = mask[off];
    tile[r][c] = mk ? (_Float16)(__expf(-gamma * tv) * 1.4426950408889634f)
                    : (_Float16)(-30000.0f);
  }
  __syncthreads();
#pragma unroll
  for (int it = 0; it < 16; ++it) {
    int r = r0 * 16 + it;
    biasT[((size_t)b * S_ + j0 + r) * S_ + i0 + c] = tile[c][r];
  }
}

// ---------------- GEMM: C[M][1024] = (A[M][1024] @ Bt[1024][1024]^T + bias) * scale
template<bool F32OUT>
__global__ __launch_bounds__(256, 3) void gemm_bt(
    const _Float16* __restrict__ A,
    const _Float16* __restrict__ Bt,
    const float*    __restrict__ bias,
    void*           __restrict__ Cout,
    float scale)
{
  __shared__ __align__(16) _Float16 Alds[128 * 64];
  __shared__ __align__(16) _Float16 Blds[128 * 64];
  const int t = threadIdx.x;
  const int lane = t & 63, w = t >> 6;
  const int wm = w >> 1, wn = w & 1;
  const int m0 = blockIdx.x * 128, n0 = blockIdx.y * 128;
  const int ll = lane & 15, lg = lane >> 4;
  f4 acc[4][4] = {};

  for (int kt = 0; kt < 1024; kt += 64) {
    __syncthreads();
#pragma unroll
    for (int i = 0; i < 4; ++i) {
      int slot = i * 256 + t;
      int r = slot >> 3;
      int gs = ((slot & 7) ^ (r & 7)) * 8;
      __builtin_amdgcn_global_load_lds(AS1(A  + (size_t)(m0 + r) * 1024 + kt + gs),
                                       AS3((char*)Alds + (i * 256 + w * 64) * 16), 16, 0, 0);
      __builtin_amdgcn_global_load_lds(AS1(Bt + (size_t)(n0 + r) * 1024 + kt + gs),
                                       AS3((char*)Blds + (i * 256 + w * 64) * 16), 16, 0, 0);
    }
    __syncthreads();
#pragma unroll
    for (int ks = 0; ks < 2; ++ks) {
      h8 af[4], bf[4];
#pragma unroll
      for (int im = 0; im < 4; ++im) {
        int R = wm * 64 + im * 16 + ll;
        af[im] = *(const h8*)((const char*)Alds + R * 128 + (((ks * 4 + lg) ^ (R & 7)) << 4));
      }
#pragma unroll
      for (int in = 0; in < 4; ++in) {
        int R = wn * 64 + in * 16 + ll;
        bf[in] = *(const h8*)((const char*)Blds + R * 128 + (((ks * 4 + lg) ^ (R & 7)) << 4));
      }
#pragma unroll
      for (int im = 0; im < 4; ++im)
#pragma unroll
        for (int in = 0; in < 4; ++in)
          acc[im][in] = mfma16(af[im], bf[in], acc[im][in]);
    }
  }
#pragma unroll
  for (int im = 0; im < 4; ++im)
#pragma unroll
    for (int in = 0; in < 4; ++in) {
      int col = n0 + wn * 64 + in * 16 + ll;
      float bv = bias[col];
#pragma unroll
      for (int r = 0; r < 4; ++r) {
        int row = m0 + wm * 64 + im * 16 + lg * 4 + r;
        float vv = (acc[im][in][r] + bv) * scale;
        if constexpr (F32OUT) ((float*)Cout)[(size_t)row * 1024 + col] = vv;
        else ((_Float16*)Cout)[(size_t)row * 1024 + col] = (_Float16)vv;
      }
    }
}

// ---------------- V transpose: Vp[b*S+s][h*64+hd] -> Vt[(b*16+h)*64+hd][s] ----------------
__global__ __launch_bounds__(256) void transpose_v(
    const _Float16* __restrict__ Vp, _Float16* __restrict__ Vt)
{
  __shared__ __align__(16) short tile[64][72];
  const int blk = blockIdx.x;
  const int b = blk >> 9, h = (blk >> 5) & 15, st = blk & 31;
  const int s0 = st * 64, t = threadIdx.x;
#pragma unroll
  for (int it = 0; it < 2; ++it) {
    int slot = it * 256 + t;
    int r = slot >> 3, c = slot & 7;
    s8 v = *(const s8*)(Vp + (size_t)(b * S_ + s0 + r) * D_ + h * 64 + c * 8);
    *(s8*)&tile[r][c * 8] = v;
  }
  __syncthreads();
#pragma unroll
  for (int it = 0; it < 2; ++it) {
    int slot = it * 256 + t;
    int hd = slot >> 3, c = slot & 7;
    union { short hh[8]; s8 v8; } o;
#pragma unroll
    for (int e = 0; e < 8; ++e) o.hh[e] = tile[c * 8 + e][hd];
    *(s8*)(Vt + (size_t)((b * 16 + h) * 64 + hd) * S_ + s0 + c * 8) = o.v8;
  }
}

// ---------------- fused flash attention ----------------
// Block = (b, h, 64 q-rows), 4 waves x 16 q-rows. K/V LDS-staged double-buffered
// (4 gload_lds per wave per tile), bias via register h4 gathers prefetched 1 tile
// ahead. No-max softmax: P = 2^(score'), lsum accumulated per-lane, single final
// reduce. LDS = K 2x8K | V 2x8K | P 4x2K = 40KB -> 4 blocks/CU (4 waves/SIMD).
#define KL_OFF   0
#define VL_OFF   16384
#define PL_OFF   32768

__global__ __launch_bounds__(256, 4) void attn_kernel(
    const _Float16* __restrict__ Qp,    // [8192][1024], pre-scaled by 1/(8 ln2)
    const _Float16* __restrict__ Kp,    // [8192][1024]
    const _Float16* __restrict__ Vt,    // [(b*16+h)*64+hd][2048]
    const _Float16* __restrict__ biasT, // [4][2048(k)][2048(q)], pre-scaled 1/ln2
    _Float16*       __restrict__ Oa)    // [8192][1024]
{
  __shared__ __align__(16) char lds[40960];
  const int t = threadIdx.x;
  const int lane = t & 63, w = t >> 6;
  const int ll = lane & 15, lg = lane >> 4;
  const int bid = blockIdx.x;
  const int b  = bid >> 9;
  const int h  = (bid >> 5) & 15;
  const int qg = bid & 31;
  const int q0 = qg * 64 + w * 16;      // wave q base

  const int lrow = lane >> 3;           // staging row-in-group
  const int lcs  = (lane & 7) ^ lrow;   // pre-swizzled chunk

  const _Float16* Kg = Kp + (size_t)b * S_ * D_ + h * 64;
  const _Float16* Vg = Vt + (size_t)(b * 16 + h) * 64 * S_;
  const _Float16* Bg = biasT + (size_t)b * S_ * S_ + q0 + lg * 4;

  char* pbase = lds + PL_OFF + w * 2048;

  // Q a-frags hoisted
  const size_t qrow = (size_t)(b * S_ + q0 + ll) * D_ + h * 64;
  h8 qf0 = *(const h8*)(Qp + qrow + lg * 8);
  h8 qf1 = *(const h8*)(Qp + qrow + 32 + lg * 8);

  float lsum[4] = {0.f, 0.f, 0.f, 0.f};
  f4 accO[4] = {};                      // O^T[d = df*16+lg*4+r][q-row = ll]

  // stage one 64-k K/V tile: wave w owns instrs w*4..w*4+3 (16 x 1KB total)
  auto STAGE = [&](int kt, int bufb) {
#pragma unroll
    for (int j = 0; j < 4; ++j) {
      int i = w * 4 + j;                // 0..15
      int g = i & 7;
      int row8 = g * 8 + lrow;
      const _Float16* src;
      char* dst;
      if (i < 8) {
        src = Kg + (size_t)(kt + row8) * D_ + lcs * 8;
        dst = lds + KL_OFF + bufb * 8192 + g * 1024;
      } else {
        src = Vg + (size_t)row8 * S_ + kt + lcs * 8;
        dst = lds + VL_OFF + bufb * 8192 + g * 1024;
      }
      __builtin_amdgcn_global_load_lds(AS1(src), AS3(dst), 16, 0, 0);
    }
  };
  auto BLOAD = [&](int kt, h4 (&dst)[4]) {
#pragma unroll
    for (int jf = 0; jf < 4; ++jf)
      dst[jf] = *(const h4*)(Bg + (size_t)(kt + 16 * jf + ll) * S_);
  };

  h4 bcur[4], bnext[4];

  // prologue
  STAGE(0, 0);
  BLOAD(0, bcur);
  asm volatile("s_waitcnt vmcnt(0)" ::: "memory");
  __builtin_amdgcn_sched_barrier(0);
  __builtin_amdgcn_s_barrier();
  __builtin_amdgcn_sched_barrier(0);

  for (int tt = 0; tt < 32; ++tt) {
    const int bufb = tt & 1;
    if (tt < 31) {
      STAGE((tt + 1) * 64, bufb ^ 1);
      BLOAD((tt + 1) * 64, bnext);
      asm volatile("s_waitcnt vmcnt(12)" ::: "memory");
    } else {
      asm volatile("s_waitcnt vmcnt(0)" ::: "memory");
    }
    __builtin_amdgcn_sched_barrier(0);
    __builtin_amdgcn_s_barrier();       // tile tt resident for all waves
    __builtin_amdgcn_sched_barrier(0);

    const char* Kb = lds + KL_OFF + bufb * 8192;
    const char* Vb = lds + VL_OFF + bufb * 8192;

    // S = QK^T  [q = lg*4+r][k = 16jf+ll]
    f4 accS[4] = {};
#pragma unroll
    for (int jf = 0; jf < 4; ++jf) {
      int row = jf * 16 + ll;
      h8 k0 = *(const h8*)(Kb + row * 128 + (((lg)     ^ (row & 7)) << 4));
      h8 k1 = *(const h8*)(Kb + row * 128 + (((4 + lg) ^ (row & 7)) << 4));
      accS[jf] = mfma16(qf0, k0, accS[jf]);
      accS[jf] = mfma16(qf1, k1, accS[jf]);
    }

    // P = 2^(S + bias'); lsum per-lane; write P (f16) to swizzled LDS
#pragma unroll
    for (int jf = 0; jf < 4; ++jf)
#pragma unroll
      for (int r = 0; r < 4; ++r) {
        float sc = accS[jf][r] + (float)bcur[jf][r];
        float p;
        asm("v_exp_f32 %0, %1" : "=v"(p) : "v"(sc));
        lsum[r] += p;
        int i = lg * 4 + r, j = ll + 16 * jf;
        *(_Float16*)(pbase + i * 128 + ((2 * j) ^ ((i & 7) << 4))) = (_Float16)p;
      }
#pragma unroll
    for (int jf = 0; jf < 4; ++jf) bcur[jf] = bnext[jf];

    // O^T += V^T . P^T
#pragma unroll
    for (int ks = 0; ks < 2; ++ks) {
      h8 pf = *(const h8*)(pbase + ll * 128 + ((ks * 64 + lg * 16) ^ ((ll & 7) << 4)));
#pragma unroll
      for (int df = 0; df < 4; ++df) {
        int vrow = df * 16 + ll;
        h8 vfr = *(const h8*)(Vb + vrow * 128 + (((ks * 4 + lg) ^ (vrow & 7)) << 4));
        accO[df] = mfma16(vfr, pf, accO[df]);
      }
    }

    __builtin_amdgcn_sched_barrier(0);
    __builtin_amdgcn_s_barrier();       // all waves done reading buf[bufb]
    __builtin_amdgcn_sched_barrier(0);
  }

  // single final reduce: row-sum over the 16 ll-lanes
#pragma unroll
  for (int d = 1; d < 16; d <<= 1)
#pragma unroll
    for (int r = 0; r < 4; ++r)
      lsum[r] += __shfl_xor(lsum[r], d);

  // move lsum (row = lg*4+r layout) to row = ll layout, in-register
  float ls = lsum[0];
  ls = ((ll & 3) == 1) ? lsum[1] : ls;
  ls = ((ll & 3) == 2) ? lsum[2] : ls;
  ls = ((ll & 3) == 3) ? lsum[3] : ls;
  float lf = __shfl(ls, ((ll >> 2) << 4) + ll);
  float linv = 1.0f / lf;
#pragma unroll
  for (int df = 0; df < 4; ++df)
#pragma unroll
    for (int r = 0; r < 4; ++r) {
      size_t orow = (size_t)(b * S_ + q0 + ll) * D_ + h * 64 + df * 16 + lg * 4 + r;
      Oa[orow] = (_Float16)(accO[df][r] * linv);
    }
}

// ---------------- launcher ----------------
extern "C" void kernel_launch(void* const* d_in, const int* in_sizes, int n_in,
                              void* d_out, int out_size, void* d_ws, size_t ws_size,
                              hipStream_t stream) {
  const float* q    = (const float*)d_in[0];
  const float* k    = (const float*)d_in[1];
  const float* v    = (const float*)d_in[2];
  const float* td   = (const float*)d_in[3];
  const int*   mask = (const int*)d_in[4];
  const float* Wq   = (const float*)d_in[5];
  const float* bq   = (const float*)d_in[6];
  const float* Wk   = (const float*)d_in[7];
  const float* bk   = (const float*)d_in[8];
  const float* Wv   = (const float*)d_in[9];
  const float* bv   = (const float*)d_in[10];
  const float* Wo   = (const float*)d_in[11];
  const float* bo   = (const float*)d_in[12];
  const float* gm   = (const float*)d_in[13];

  const size_t MD = (size_t)M_ * D_;      // 8388608
  const size_t WW = (size_t)D_ * D_;      // 1048576
  if (ws_size < (8 * MD + 4 * WW) * sizeof(_Float16)) return;

  _Float16* base = (_Float16*)d_ws;
  _Float16* qh = base;
  _Float16* kh = qh + MD;
  _Float16* vh = kh + MD;
  _Float16* wq = vh + MD;
  _Float16* wk = wq + WW;
  _Float16* wv = wk + WW;
  _Float16* wo = wv + WW;
  _Float16* Qp = wo + WW;
  _Float16* Kp = Qp + MD;
  _Float16* Vp = Kp + MD;
  _Float16* Vt = Vp + MD;
  _Float16* Oa = Vt + MD;
  _Float16* biasT = qh;   // reuse qh+kh (2*MD = B*S*S) after gemmQ/gemmK consume them

  CastArgs ca;
  ca.src[0] = q;  ca.src[1] = k;  ca.src[2] = v;
  ca.src[3] = Wq; ca.src[4] = Wk; ca.src[5] = Wv; ca.src[6] = Wo;
  ca.dst[0] = qh; ca.dst[1] = kh; ca.dst[2] = vh;
  ca.dst[3] = wq; ca.dst[4] = wk; ca.dst[5] = wv; ca.dst[6] = wo;
  int sizes[7] = {(int)(MD / 8), (int)(MD / 8), (int)(MD / 8),
                  (int)(WW / 8), (int)(WW / 8), (int)(WW / 8), (int)(WW / 8)};
  int c = 0; ca.cum[0] = 0;
  for (int i = 0; i < 7; ++i) { c += sizes[i]; ca.cum[i + 1] = c; }
  cast_kernel<<<(c + 255) / 256, 256, 0, stream>>>(ca);

  dim3 gg(64, 8);
  // Q scale = (1/sqrt(64)) * (1/ln2) so softmax exp becomes a bare v_exp_f32 (2^x)
  gemm_bt<false><<<gg, 256, 0, stream>>>(qh, wq, bq, Qp, 0.18033688011112042f);
  gemm_bt<false><<<gg, 256, 0, stream>>>(kh, wk, bk, Kp, 1.0f);
  bias_kernel<<<4096, 256, 0, stream>>>(td, mask, gm, biasT);      // overwrites qh/kh
  gemm_bt<false><<<gg, 256, 0, stream>>>(vh, wv, bv, Vp, 1.0f);
  transpose_v<<<2048, 256, 0, stream>>>(Vp, Vt);
  attn_kernel<<<2048, 256, 0, stream>>>(Qp, Kp, Vt, biasT, Oa);
  gemm_bt<true><<<gg, 256, 0, stream>>>(Oa, wo, bo, d_out, 1.0f);
}

// Round 8
// 325.272 us; speedup vs baseline: 2.2638x; 1.0724x over previous
//
#include <hip/hip_runtime.h>
#include <hip/hip_bf16.h>

#define B_ 4
#define S_ 2048
#define D_ 1024
#define H_ 16
#define M_ 8192   // B_*S_

typedef __attribute__((ext_vector_type(8))) _Float16 h8;
typedef __attribute__((ext_vector_type(4))) _Float16 h4;
typedef __attribute__((ext_vector_type(2))) __fp16   fp16x2;
typedef __attribute__((ext_vector_type(8))) short    s8;
typedef __attribute__((ext_vector_type(4))) float    f4;

#define AS1(p) ((const __attribute__((address_space(1))) void*)(p))
#define AS3(p) ((__attribute__((address_space(3))) void*)(p))

__device__ __forceinline__ f4 mfma16(h8 a, h8 b, f4 c) {
  return __builtin_amdgcn_mfma_f32_16x16x32_f16(a, b, c, 0, 0, 0);
}

// ---------------- cast f32 -> f16 (q,k,v,Wq,Wk,Wv,Wo) ----------------
struct CastArgs {
  const float* src[7];
  _Float16*    dst[7];
  int cum[8];
};

__global__ __launch_bounds__(256) void cast_kernel(CastArgs a) {
  int idx = blockIdx.x * 256 + threadIdx.x;
  if (idx >= a.cum[7]) return;
  int seg = 0;
#pragma unroll
  for (int s = 1; s < 7; ++s) seg += (idx >= a.cum[s]) ? 1 : 0;
  size_t off = (size_t)(idx - a.cum[seg]) * 8;
  const float4* sp = (const float4*)(a.src[seg] + off);
  float4 u = sp[0], v = sp[1];
  union { _Float16 h[8]; h8 v8; } o;
  o.h[0] = (_Float16)u.x; o.h[1] = (_Float16)u.y;
  o.h[2] = (_Float16)u.z; o.h[3] = (_Float16)u.w;
  o.h[4] = (_Float16)v.x; o.h[5] = (_Float16)v.y;
  o.h[6] = (_Float16)v.z; o.h[7] = (_Float16)v.w;
  *(h8*)(a.dst[seg] + off) = o.v8;
}

// ---------------- bias precompute (no transpose) ----------------
// biasN[b][i(q)][j(k)] = mask ? exp(-gamma*td)/ln2 : -30000   (f16)
__global__ __launch_bounds__(256) void bias_kernel(
    const float* __restrict__ td, const int* __restrict__ mask,
    const float* __restrict__ gptr, _Float16* __restrict__ biasN)
{
  const float gamma = gptr[0];
  size_t idx = (size_t)blockIdx.x * 256 + threadIdx.x;
  size_t off = idx * 8;
  const float4* tp = (const float4*)(td + off);
  const int4*   mp = (const int4*)(mask + off);
  float4 t0 = tp[0], t1 = tp[1];
  int4   m0 = mp[0], m1 = mp[1];
  union { _Float16 h[8]; h8 v8; } o;
  o.h[0] = m0.x ? (_Float16)(__expf(-gamma * t0.x) * 1.4426950408889634f) : (_Float16)(-30000.0f);
  o.h[1] = m0.y ? (_Float16)(__expf(-gamma * t0.y) * 1.4426950408889634f) : (_Float16)(-30000.0f);
  o.h[2] = m0.z ? (_Float16)(__expf(-gamma * t0.z) * 1.4426950408889634f) : (_Float16)(-30000.0f);
  o.h[3] = m0.w ? (_Float16)(__expf(-gamma * t0.w) * 1.4426950408889634f) : (_Float16)(-30000.0f);
  o.h[4] = m1.x ? (_Float16)(__expf(-gamma * t1.x) * 1.4426950408889634f) : (_Float16)(-30000.0f);
  o.h[5] = m1.y ? (_Float16)(__expf(-gamma * t1.y) * 1.4426950408889634f) : (_Float16)(-30000.0f);
  o.h[6] = m1.z ? (_Float16)(__expf(-gamma * t1.z) * 1.4426950408889634f) : (_Float16)(-30000.0f);
  o.h[7] = m1.w ? (_Float16)(__expf(-gamma * t1.w) * 1.4426950408889634f) : (_Float16)(-30000.0f);
  *(h8*)(biasN + off) = o.v8;
}

// ---------------- GEMM: C[M][1024] = (A[M][1024] @ Bt[1024][1024]^T + bias) * scale
template<bool F32OUT>
__global__ __launch_bounds__(256, 3) void gemm_bt(
    const _Float16* __restrict__ A,
    const _Float16* __restrict__ Bt,
    const float*    __restrict__ bias,
    void*           __restrict__ Cout,
    float scale)
{
  __shared__ __align__(16) _Float16 Alds[128 * 64];
  __shared__ __align__(16) _Float16 Blds[128 * 64];
  const int t = threadIdx.x;
  const int lane = t & 63, w = t >> 6;
  const int wm = w >> 1, wn = w & 1;
  const int m0 = blockIdx.x * 128, n0 = blockIdx.y * 128;
  const int ll = lane & 15, lg = lane >> 4;
  f4 acc[4][4] = {};

  for (int kt = 0; kt < 1024; kt += 64) {
    __syncthreads();
#pragma unroll
    for (int i = 0; i < 4; ++i) {
      int slot = i * 256 + t;
      int r = slot >> 3;
      int gs = ((slot & 7) ^ (r & 7)) * 8;
      __builtin_amdgcn_global_load_lds(AS1(A  + (size_t)(m0 + r) * 1024 + kt + gs),
                                       AS3((char*)Alds + (i * 256 + w * 64) * 16), 16, 0, 0);
      __builtin_amdgcn_global_load_lds(AS1(Bt + (size_t)(n0 + r) * 1024 + kt + gs),
                                       AS3((char*)Blds + (i * 256 + w * 64) * 16), 16, 0, 0);
    }
    __syncthreads();
#pragma unroll
    for (int ks = 0; ks < 2; ++ks) {
      h8 af[4], bf[4];
#pragma unroll
      for (int im = 0; im < 4; ++im) {
        int R = wm * 64 + im * 16 + ll;
        af[im] = *(const h8*)((const char*)Alds + R * 128 + (((ks * 4 + lg) ^ (R & 7)) << 4));
      }
#pragma unroll
      for (int in = 0; in < 4; ++in) {
        int R = wn * 64 + in * 16 + ll;
        bf[in] = *(const h8*)((const char*)Blds + R * 128 + (((ks * 4 + lg) ^ (R & 7)) << 4));
      }
#pragma unroll
      for (int im = 0; im < 4; ++im)
#pragma unroll
        for (int in = 0; in < 4; ++in)
          acc[im][in] = mfma16(af[im], bf[in], acc[im][in]);
    }
  }
#pragma unroll
  for (int im = 0; im < 4; ++im)
#pragma unroll
    for (int in = 0; in < 4; ++in) {
      int col = n0 + wn * 64 + in * 16 + ll;
      float bv = bias[col];
#pragma unroll
      for (int r = 0; r < 4; ++r) {
        int row = m0 + wm * 64 + im * 16 + lg * 4 + r;
        float vv = (acc[im][in][r] + bv) * scale;
        if constexpr (F32OUT) ((float*)Cout)[(size_t)row * 1024 + col] = vv;
        else ((_Float16*)Cout)[(size_t)row * 1024 + col] = (_Float16)vv;
      }
    }
}

// ---------------- V transpose: Vp[b*S+s][h*64+hd] -> Vt[(b*16+h)*64+hd][s] ----------------
__global__ __launch_bounds__(256) void transpose_v(
    const _Float16* __restrict__ Vp, _Float16* __restrict__ Vt)
{
  __shared__ __align__(16) short tile[64][72];
  const int blk = blockIdx.x;
  const int b = blk >> 9, h = (blk >> 5) & 15, st = blk & 31;
  const int s0 = st * 64, t = threadIdx.x;
#pragma unroll
  for (int it = 0; it < 2; ++it) {
    int slot = it * 256 + t;
    int r = slot >> 3, c = slot & 7;
    s8 v = *(const s8*)(Vp + (size_t)(b * S_ + s0 + r) * D_ + h * 64 + c * 8);
    *(s8*)&tile[r][c * 8] = v;
  }
  __syncthreads();
#pragma unroll
  for (int it = 0; it < 2; ++it) {
    int slot = it * 256 + t;
    int hd = slot >> 3, c = slot & 7;
    union { short hh[8]; s8 v8; } o;
#pragma unroll
    for (int e = 0; e < 8; ++e) o.hh[e] = tile[c * 8 + e][hd];
    *(s8*)(Vt + (size_t)((b * 16 + h) * 64 + hd) * S_ + s0 + c * 8) = o.v8;
  }
}

// ---------------- fused flash attention ----------------
// Round-5 LOGIC (swapped QK^T, bias C-init, packed P, scalar lsum) under
// compiler-managed sync only: ONE __syncthreads() per k-tile (drains vmcnt
// for the mid-body STAGE of tile tt+1 and provides WAR protection for the
// double buffer). No inline-asm waitcnt, no raw s_barrier, no sched_barrier
// — diagnostic for the round-6/7 failure (logic vs scheduling hazard).
#define KL_OFF   0
#define VL_OFF   16384
#define PL_OFF   32768

__global__ __launch_bounds__(256, 4) void attn_kernel(
    const _Float16* __restrict__ Qp,    // [8192][1024], pre-scaled by 1/(8 ln2)
    const _Float16* __restrict__ Kp,    // [8192][1024]
    const _Float16* __restrict__ Vt,    // [(b*16+h)*64+hd][2048]
    const _Float16* __restrict__ biasN, // [4][2048(q)][2048(k)], pre-scaled 1/ln2
    _Float16*       __restrict__ Oa)    // [8192][1024]
{
  __shared__ __align__(16) char lds[40960];
  const int t = threadIdx.x;
  const int lane = t & 63, w = t >> 6;
  const int ll = lane & 15, lg = lane >> 4;
  const int bid = blockIdx.x;
  const int b  = bid >> 9;
  const int h  = (bid >> 5) & 15;
  const int qg = bid & 31;
  const int q0 = qg * 64 + w * 16;      // wave q base

  const int lrow = lane >> 3;           // staging row-in-group
  const int lcs  = (lane & 7) ^ lrow;   // pre-swizzled chunk

  const _Float16* Kg = Kp + (size_t)b * S_ * D_ + h * 64;
  const _Float16* Vg = Vt + (size_t)(b * 16 + h) * 64 * S_;
  const _Float16* Bg = biasN + ((size_t)b * S_ + q0 + ll) * S_;  // per-lane row q

  char* pbase = lds + PL_OFF + w * 2048;

  // Q fragments (B-operand of swapped QK)
  const size_t qrow = (size_t)(b * S_ + q0 + ll) * D_ + h * 64;
  h8 qf0 = *(const h8*)(Qp + qrow + lg * 8);
  h8 qf1 = *(const h8*)(Qp + qrow + 32 + lg * 8);

  float lsum = 0.f;                     // all elements of this lane are q = ll
  f4 accO[4] = {};                      // O^T[d = df*16+lg*4+r][q = ll]

  auto STAGE = [&](int kt, int bufb) {
#pragma unroll
    for (int j = 0; j < 4; ++j) {
      int i = w * 4 + j;                // 0..15
      int g = i & 7;
      int row8 = g * 8 + lrow;
      const _Float16* src;
      char* dst;
      if (i < 8) {
        src = Kg + (size_t)(kt + row8) * D_ + lcs * 8;
        dst = lds + KL_OFF + bufb * 8192 + g * 1024;
      } else {
        src = Vg + (size_t)row8 * S_ + kt + lcs * 8;
        dst = lds + VL_OFF + bufb * 8192 + g * 1024;
      }
      __builtin_amdgcn_global_load_lds(AS1(src), AS3(dst), 16, 0, 0);
    }
  };
  auto BLOAD = [&](int kt, h4 (&dst)[4]) {
#pragma unroll
    for (int jf = 0; jf < 4; ++jf)
      dst[jf] = *(const h4*)(Bg + kt + 16 * jf + lg * 4);
  };

  auto BODY = [&](int tt, h4 (&bc)[4], h4 (&bn)[4]) {
    const int bufb = tt & 1;
    const char* Kb = lds + KL_OFF + bufb * 8192;
    const char* Vb = lds + VL_OFF + bufb * 8192;

    // S^T = K . Q^T, bias as MFMA C-init.
    // accS[jf][r] = S^T[k = 16jf+4lg+r][q = ll]
    f4 accS[4];
#pragma unroll
    for (int jf = 0; jf < 4; ++jf) {
      accS[jf][0] = (float)bc[jf][0];
      accS[jf][1] = (float)bc[jf][1];
      accS[jf][2] = (float)bc[jf][2];
      accS[jf][3] = (float)bc[jf][3];
    }
#pragma unroll
    for (int jf = 0; jf < 4; ++jf) {
      int row = jf * 16 + ll;
      h8 k0 = *(const h8*)(Kb + row * 128 + (((lg)     ^ (row & 7)) << 4));
      h8 k1 = *(const h8*)(Kb + row * 128 + (((4 + lg) ^ (row & 7)) << 4));
      accS[jf] = mfma16(k0, qf0, accS[jf]);
      accS[jf] = mfma16(k1, qf1, accS[jf]);
    }

    // issue next tile mid-body: drained by the end-of-body __syncthreads,
    // overlapped with softmax + PV below
    if (tt < 31) {
      STAGE((tt + 1) * 64, bufb ^ 1);
      BLOAD((tt + 1) * 64, bn);
    }

    // P^T = 2^(S^T); pack pairs along k (regs) -> one ds_write_b64 per jf
#pragma unroll
    for (int jf = 0; jf < 4; ++jf) {
      float p0, p1, p2, p3;
      asm("v_exp_f32 %0, %1" : "=v"(p0) : "v"(accS[jf][0]));
      asm("v_exp_f32 %0, %1" : "=v"(p1) : "v"(accS[jf][1]));
      asm("v_exp_f32 %0, %1" : "=v"(p2) : "v"(accS[jf][2]));
      asm("v_exp_f32 %0, %1" : "=v"(p3) : "v"(accS[jf][3]));
      lsum += (p0 + p1) + (p2 + p3);
      union { fp16x2 h[2]; unsigned long long u; } wv;
      wv.h[0] = __builtin_amdgcn_cvt_pkrtz(p0, p1);
      wv.h[1] = __builtin_amdgcn_cvt_pkrtz(p2, p3);
      // P_lds[q=ll][k = 16jf+4lg .. +3], swizzled byte ^= (ll&7)<<4
      *(unsigned long long*)(pbase + ll * 128 + ((32 * jf + 8 * lg) ^ ((ll & 7) << 4))) = wv.u;
    }

    // O^T += V^T . P^T
#pragma unroll
    for (int ks = 0; ks < 2; ++ks) {
      h8 pf = *(const h8*)(pbase + ll * 128 + ((ks * 64 + lg * 16) ^ ((ll & 7) << 4)));
#pragma unroll
      for (int df = 0; df < 4; ++df) {
        int vrow = df * 16 + ll;
        h8 vfr = *(const h8*)(Vb + vrow * 128 + (((ks * 4 + lg) ^ (vrow & 7)) << 4));
        accO[df] = mfma16(vfr, pf, accO[df]);
      }
    }

    __syncthreads();   // drains stage(tt+1) (vmcnt0+lgkmcnt0) + WAR for buf[bufb]
  };

  h4 bA[4], bB[4];

  // prologue
  STAGE(0, 0);
  BLOAD(0, bA);
  __syncthreads();     // tile 0 resident for all waves

  for (int tt = 0; tt < 32; tt += 2) {  // 2x unroll: bias regs ping-pong
    BODY(tt,     bA, bB);
    BODY(tt + 1, bB, bA);
  }

  // final: sum partials across the 4 lg-groups holding the same q = ll
  lsum += __shfl_xor(lsum, 16);
  lsum += __shfl_xor(lsum, 32);
  float linv = 1.0f / lsum;
#pragma unroll
  for (int df = 0; df < 4; ++df)
#pragma unroll
    for (int r = 0; r < 4; ++r) {
      size_t orow = (size_t)(b * S_ + q0 + ll) * D_ + h * 64 + df * 16 + lg * 4 + r;
      Oa[orow] = (_Float16)(accO[df][r] * linv);
    }
}

// ---------------- launcher ----------------
extern "C" void kernel_launch(void* const* d_in, const int* in_sizes, int n_in,
                              void* d_out, int out_size, void* d_ws, size_t ws_size,
                              hipStream_t stream) {
  const float* q    = (const float*)d_in[0];
  const float* k    = (const float*)d_in[1];
  const float* v    = (const float*)d_in[2];
  const float* td   = (const float*)d_in[3];
  const int*   mask = (const int*)d_in[4];
  const float* Wq   = (const float*)d_in[5];
  const float* bq   = (const float*)d_in[6];
  const float* Wk   = (const float*)d_in[7];
  const float* bk   = (const float*)d_in[8];
  const float* Wv   = (const float*)d_in[9];
  const float* bv   = (const float*)d_in[10];
  const float* Wo   = (const float*)d_in[11];
  const float* bo   = (const float*)d_in[12];
  const float* gm   = (const float*)d_in[13];

  const size_t MD = (size_t)M_ * D_;      // 8388608
  const size_t WW = (size_t)D_ * D_;      // 1048576
  if (ws_size < (8 * MD + 4 * WW) * sizeof(_Float16)) return;

  _Float16* base = (_Float16*)d_ws;
  _Float16* qh = base;
  _Float16* kh = qh + MD;
  _Float16* vh = kh + MD;
  _Float16* wq = vh + MD;
  _Float16* wk = wq + WW;
  _Float16* wv = wk + WW;
  _Float16* wo = wv + WW;
  _Float16* Qp = wo + WW;
  _Float16* Kp = Qp + MD;
  _Float16* Vp = Kp + MD;
  _Float16* Vt = Vp + MD;
  _Float16* Oa = Vt + MD;
  _Float16* biasN = qh;   // reuse qh+kh (2*MD = B*S*S) after gemmQ/gemmK consume them

  CastArgs ca;
  ca.src[0] = q;  ca.src[1] = k;  ca.src[2] = v;
  ca.src[3] = Wq; ca.src[4] = Wk; ca.src[5] = Wv; ca.src[6] = Wo;
  ca.dst[0] = qh; ca.dst[1] = kh; ca.dst[2] = vh;
  ca.dst[3] = wq; ca.dst[4] = wk; ca.dst[5] = wv; ca.dst[6] = wo;
  int sizes[7] = {(int)(MD / 8), (int)(MD / 8), (int)(MD / 8),
                  (int)(WW / 8), (int)(WW / 8), (int)(WW / 8), (int)(WW / 8)};
  int c = 0; ca.cum[0] = 0;
  for (int i = 0; i < 7; ++i) { c += sizes[i]; ca.cum[i + 1] = c; }
  cast_kernel<<<(c + 255) / 256, 256, 0, stream>>>(ca);

  dim3 gg(64, 8);
  // Q scale = (1/sqrt(64)) * (1/ln2) so softmax exp becomes a bare v_exp_f32 (2^x)
  gemm_bt<false><<<gg, 256, 0, stream>>>(qh, wq, bq, Qp, 0.18033688011112042f);
  gemm_bt<false><<<gg, 256, 0, stream>>>(kh, wk, bk, Kp, 1.0f);
  bias_kernel<<<8192, 256, 0, stream>>>(td, mask, gm, biasN);      // overwrites qh/kh
  gemm_bt<false><<<gg, 256, 0, stream>>>(vh, wv, bv, Vp, 1.0f);
  transpose_v<<<2048, 256, 0, stream>>>(Vp, Vt);
  attn_kernel<<<2048, 256, 0, stream>>>(Qp, Kp, Vt, biasN, Oa);
  gemm_bt<true><<<gg, 256, 0, stream>>>(Oa, wo, bo, d_out, 1.0f);
}

// Round 10
// 320.251 us; speedup vs baseline: 2.2993x; 1.0157x over previous
//
#include <hip/hip_runtime.h>
#include <hip/hip_bf16.h>

#define B_ 4
#define S_ 2048
#define D_ 1024
#define H_ 16
#define M_ 8192   // B_*S_

typedef __attribute__((ext_vector_type(8))) _Float16 h8;
typedef __attribute__((ext_vector_type(4))) _Float16 h4;
typedef __attribute__((ext_vector_type(2))) __fp16   fp16x2;
typedef __attribute__((ext_vector_type(8))) short    s8;
typedef __attribute__((ext_vector_type(4))) float    f4;

#define AS1(p) ((const __attribute__((address_space(1))) void*)(p))
#define AS3(p) ((__attribute__((address_space(3))) void*)(p))

__device__ __forceinline__ f4 mfma16(h8 a, h8 b, f4 c) {
  return __builtin_amdgcn_mfma_f32_16x16x32_f16(a, b, c, 0, 0, 0);
}

// ---------------- cast f32 -> f16 (q,k,v,Wq,Wk,Wv,Wo) ----------------
struct CastArgs {
  const float* src[7];
  _Float16*    dst[7];
  int cum[8];
};

__global__ __launch_bounds__(256) void cast_kernel(CastArgs a) {
  int idx = blockIdx.x * 256 + threadIdx.x;
  if (idx >= a.cum[7]) return;
  int seg = 0;
#pragma unroll
  for (int s = 1; s < 7; ++s) seg += (idx >= a.cum[s]) ? 1 : 0;
  size_t off = (size_t)(idx - a.cum[seg]) * 8;
  const float4* sp = (const float4*)(a.src[seg] + off);
  float4 u = sp[0], v = sp[1];
  union { _Float16 h[8]; h8 v8; } o;
  o.h[0] = (_Float16)u.x; o.h[1] = (_Float16)u.y;
  o.h[2] = (_Float16)u.z; o.h[3] = (_Float16)u.w;
  o.h[4] = (_Float16)v.x; o.h[5] = (_Float16)v.y;
  o.h[6] = (_Float16)v.z; o.h[7] = (_Float16)v.w;
  *(h8*)(a.dst[seg] + off) = o.v8;
}

// ---------------- bias precompute (no transpose) ----------------
// biasN[b][i(q)][j(k)] = mask ? exp(-gamma*td)/ln2 : -30000   (f16)
__global__ __launch_bounds__(256) void bias_kernel(
    const float* __restrict__ td, const int* __restrict__ mask,
    const float* __restrict__ gptr, _Float16* __restrict__ biasN)
{
  const float gamma = gptr[0];
  size_t idx = (size_t)blockIdx.x * 256 + threadIdx.x;
  size_t off = idx * 8;
  const float4* tp = (const float4*)(td + off);
  const int4*   mp = (const int4*)(mask + off);
  float4 t0 = tp[0], t1 = tp[1];
  int4   m0 = mp[0], m1 = mp[1];
  union { _Float16 h[8]; h8 v8; } o;
  o.h[0] = m0.x ? (_Float16)(__expf(-gamma * t0.x) * 1.4426950408889634f) : (_Float16)(-30000.0f);
  o.h[1] = m0.y ? (_Float16)(__expf(-gamma * t0.y) * 1.4426950408889634f) : (_Float16)(-30000.0f);
  o.h[2] = m0.z ? (_Float16)(__expf(-gamma * t0.z) * 1.4426950408889634f) : (_Float16)(-30000.0f);
  o.h[3] = m0.w ? (_Float16)(__expf(-gamma * t0.w) * 1.4426950408889634f) : (_Float16)(-30000.0f);
  o.h[4] = m1.x ? (_Float16)(__expf(-gamma * t1.x) * 1.4426950408889634f) : (_Float16)(-30000.0f);
  o.h[5] = m1.y ? (_Float16)(__expf(-gamma * t1.y) * 1.4426950408889634f) : (_Float16)(-30000.0f);
  o.h[6] = m1.z ? (_Float16)(__expf(-gamma * t1.z) * 1.4426950408889634f) : (_Float16)(-30000.0f);
  o.h[7] = m1.w ? (_Float16)(__expf(-gamma * t1.w) * 1.4426950408889634f) : (_Float16)(-30000.0f);
  *(h8*)(biasN + off) = o.v8;
}

// ---------------- GEMM: C[M][1024] = (A[M][1024] @ Bt[1024][1024]^T + bias) * scale
// MODE 0: f16 row-major out. MODE 1: f32 row-major out.
// MODE 2: f16 out stored TRANSPOSED per-head for V: Vt[(b*16+h)*64+hd][s].
//         (fragment's 4 r-values are s-consecutive -> one aligned 8B store)
template<int MODE>
__global__ __launch_bounds__(256, 3) void gemm_bt(
    const _Float16* __restrict__ A,
    const _Float16* __restrict__ Bt,
    const float*    __restrict__ bias,
    void*           __restrict__ Cout,
    float scale)
{
  __shared__ __align__(16) _Float16 Alds[128 * 64];
  __shared__ __align__(16) _Float16 Blds[128 * 64];
  const int t = threadIdx.x;
  const int lane = t & 63, w = t >> 6;
  const int wm = w >> 1, wn = w & 1;
  const int m0 = blockIdx.x * 128, n0 = blockIdx.y * 128;
  const int ll = lane & 15, lg = lane >> 4;
  f4 acc[4][4] = {};

  for (int kt = 0; kt < 1024; kt += 64) {
    __syncthreads();
#pragma unroll
    for (int i = 0; i < 4; ++i) {
      int slot = i * 256 + t;
      int r = slot >> 3;
      int gs = ((slot & 7) ^ (r & 7)) * 8;
      __builtin_amdgcn_global_load_lds(AS1(A  + (size_t)(m0 + r) * 1024 + kt + gs),
                                       AS3((char*)Alds + (i * 256 + w * 64) * 16), 16, 0, 0);
      __builtin_amdgcn_global_load_lds(AS1(Bt + (size_t)(n0 + r) * 1024 + kt + gs),
                                       AS3((char*)Blds + (i * 256 + w * 64) * 16), 16, 0, 0);
    }
    __syncthreads();
#pragma unroll
    for (int ks = 0; ks < 2; ++ks) {
      h8 af[4], bf[4];
#pragma unroll
      for (int im = 0; im < 4; ++im) {
        int R = wm * 64 + im * 16 + ll;
        af[im] = *(const h8*)((const char*)Alds + R * 128 + (((ks * 4 + lg) ^ (R & 7)) << 4));
      }
#pragma unroll
      for (int in = 0; in < 4; ++in) {
        int R = wn * 64 + in * 16 + ll;
        bf[in] = *(const h8*)((const char*)Blds + R * 128 + (((ks * 4 + lg) ^ (R & 7)) << 4));
      }
#pragma unroll
      for (int im = 0; im < 4; ++im)
#pragma unroll
        for (int in = 0; in < 4; ++in)
          acc[im][in] = mfma16(af[im], bf[in], acc[im][in]);
    }
  }
#pragma unroll
  for (int im = 0; im < 4; ++im)
#pragma unroll
    for (int in = 0; in < 4; ++in) {
      int col = n0 + wn * 64 + in * 16 + ll;
      float bv = bias[col];
      if constexpr (MODE == 2) {
        int row0 = m0 + wm * 64 + im * 16 + lg * 4;     // 4 consecutive s values
        int bb = row0 >> 11, s = row0 & 2047;           // 128-row tile never straddles b
        union { _Float16 hh[4]; unsigned long long u; } pk;
#pragma unroll
        for (int r = 0; r < 4; ++r)
          pk.hh[r] = (_Float16)((acc[im][in][r] + bv) * scale);
        _Float16* Vt = (_Float16*)Cout;
        *(unsigned long long*)(Vt + (size_t)((bb * 16 + (col >> 6)) * 64 + (col & 63)) * S_ + s) = pk.u;
      } else {
#pragma unroll
        for (int r = 0; r < 4; ++r) {
          int row = m0 + wm * 64 + im * 16 + lg * 4 + r;
          float vv = (acc[im][in][r] + bv) * scale;
          if constexpr (MODE == 1) ((float*)Cout)[(size_t)row * 1024 + col] = vv;
          else ((_Float16*)Cout)[(size_t)row * 1024 + col] = (_Float16)vv;
        }
      }
    }
}

// ---------------- fused flash attention (round-8 validated structure) ----------
// Block = (b, h, 64 q-rows), 4 waves x 16 q-rows. K/V LDS-staged double-buffered.
// Swapped QK: accS = mfma(K,Q) = S^T, bias as MFMA C-init; P packed via
// cvt_pkrtz -> 4x ds_write_b64; lsum per-lane scalar. ONE __syncthreads per
// k-tile (drains mid-body STAGE of tile tt+1, WAR for double buffer).
// XCD-chunked block swizzle: 32 blocks sharing (b,h) -> same XCD L2.
// LDS = K 2x8K | V 2x8K | P 4x2K = 40KB -> 4 blocks/CU.
#define KL_OFF   0
#define VL_OFF   16384
#define PL_OFF   32768

__global__ __launch_bounds__(256, 4) void attn_kernel(
    const _Float16* __restrict__ Qp,    // [8192][1024], pre-scaled by 1/(8 ln2)
    const _Float16* __restrict__ Kp,    // [8192][1024]
    const _Float16* __restrict__ Vt,    // [(b*16+h)*64+hd][2048]
    const _Float16* __restrict__ biasN, // [4][2048(q)][2048(k)], pre-scaled 1/ln2
    _Float16*       __restrict__ Oa)    // [8192][1024]
{
  __shared__ __align__(16) char lds[40960];
  const int t = threadIdx.x;
  const int lane = t & 63, w = t >> 6;
  const int ll = lane & 15, lg = lane >> 4;
  // XCD-chunked swizzle (grid 2048 = 8 XCD x 256): consecutive vbid share an XCD
  const int vbid = ((int)blockIdx.x & 7) * 256 + ((int)blockIdx.x >> 3);
  const int b  = vbid >> 9;
  const int h  = (vbid >> 5) & 15;
  const int qg = vbid & 31;
  const int q0 = qg * 64 + w * 16;      // wave q base

  const int lrow = lane >> 3;           // staging row-in-group
  const int lcs  = (lane & 7) ^ lrow;   // pre-swizzled chunk

  const _Float16* Kg = Kp + (size_t)b * S_ * D_ + h * 64;
  const _Float16* Vg = Vt + (size_t)(b * 16 + h) * 64 * S_;
  const _Float16* Bg = biasN + ((size_t)b * S_ + q0 + ll) * S_;  // per-lane row q

  char* pbase = lds + PL_OFF + w * 2048;

  // Q fragments (B-operand of swapped QK)
  const size_t qrow = (size_t)(b * S_ + q0 + ll) * D_ + h * 64;
  h8 qf0 = *(const h8*)(Qp + qrow + lg * 8);
  h8 qf1 = *(const h8*)(Qp + qrow + 32 + lg * 8);

  float lsum = 0.f;                     // all elements of this lane are q = ll
  f4 accO[4] = {};                      // O^T[d = df*16+lg*4+r][q = ll]

  auto STAGE = [&](int kt, int bufb) {
#pragma unroll
    for (int j = 0; j < 4; ++j) {
      int i = w * 4 + j;                // 0..15
      int g = i & 7;
      int row8 = g * 8 + lrow;
      const _Float16* src;
      char* dst;
      if (i < 8) {
        src = Kg + (size_t)(kt + row8) * D_ + lcs * 8;
        dst = lds + KL_OFF + bufb * 8192 + g * 1024;
      } else {
        src = Vg + (size_t)row8 * S_ + kt + lcs * 8;
        dst = lds + VL_OFF + bufb * 8192 + g * 1024;
      }
      __builtin_amdgcn_global_load_lds(AS1(src), AS3(dst), 16, 0, 0);
    }
  };
  auto BLOAD = [&](int kt, h4 (&dst)[4]) {
#pragma unroll
    for (int jf = 0; jf < 4; ++jf)
      dst[jf] = *(const h4*)(Bg + kt + 16 * jf + lg * 4);
  };

  auto BODY = [&](int tt, h4 (&bc)[4], h4 (&bn)[4]) {
    const int bufb = tt & 1;
    const char* Kb = lds + KL_OFF + bufb * 8192;
    const char* Vb = lds + VL_OFF + bufb * 8192;

    // S^T = K . Q^T, bias as MFMA C-init.
    // accS[jf][r] = S^T[k = 16jf+4lg+r][q = ll]
    f4 accS[4];
#pragma unroll
    for (int jf = 0; jf < 4; ++jf) {
      accS[jf][0] = (float)bc[jf][0];
      accS[jf][1] = (float)bc[jf][1];
      accS[jf][2] = (float)bc[jf][2];
      accS[jf][3] = (float)bc[jf][3];
    }
#pragma unroll
    for (int jf = 0; jf < 4; ++jf) {
      int row = jf * 16 + ll;
      h8 k0 = *(const h8*)(Kb + row * 128 + (((lg)     ^ (row & 7)) << 4));
      h8 k1 = *(const h8*)(Kb + row * 128 + (((4 + lg) ^ (row & 7)) << 4));
      accS[jf] = mfma16(k0, qf0, accS[jf]);
      accS[jf] = mfma16(k1, qf1, accS[jf]);
    }

    // issue next tile mid-body: drained by the end-of-body __syncthreads,
    // overlapped with softmax + PV below
    if (tt < 31) {
      STAGE((tt + 1) * 64, bufb ^ 1);
      BLOAD((tt + 1) * 64, bn);
    }

    // P^T = 2^(S^T); pack pairs along k (regs) -> one ds_write_b64 per jf
#pragma unroll
    for (int jf = 0; jf < 4; ++jf) {
      float p0, p1, p2, p3;
      asm("v_exp_f32 %0, %1" : "=v"(p0) : "v"(accS[jf][0]));
      asm("v_exp_f32 %0, %1" : "=v"(p1) : "v"(accS[jf][1]));
      asm("v_exp_f32 %0, %1" : "=v"(p2) : "v"(accS[jf][2]));
      asm("v_exp_f32 %0, %1" : "=v"(p3) : "v"(accS[jf][3]));
      lsum += (p0 + p1) + (p2 + p3);
      union { fp16x2 h[2]; unsigned long long u; } wv;
      wv.h[0] = __builtin_amdgcn_cvt_pkrtz(p0, p1);
      wv.h[1] = __builtin_amdgcn_cvt_pkrtz(p2, p3);
      // P_lds[q=ll][k = 16jf+4lg .. +3], swizzled byte ^= (ll&7)<<4
      *(unsigned long long*)(pbase + ll * 128 + ((32 * jf + 8 * lg) ^ ((ll & 7) << 4))) = wv.u;
    }

    // O^T += V^T . P^T
#pragma unroll
    for (int ks = 0; ks < 2; ++ks) {
      h8 pf = *(const h8*)(pbase + ll * 128 + ((ks * 64 + lg * 16) ^ ((ll & 7) << 4)));
#pragma unroll
      for (int df = 0; df < 4; ++df) {
        int vrow = df * 16 + ll;
        h8 vfr = *(const h8*)(Vb + vrow * 128 + (((ks * 4 + lg) ^ (vrow & 7)) << 4));
        accO[df] = mfma16(vfr, pf, accO[df]);
      }
    }

    __syncthreads();   // drains stage(tt+1) (vmcnt0+lgkmcnt0) + WAR for buf[bufb]
  };

  h4 bA[4], bB[4];

  // prologue
  STAGE(0, 0);
  BLOAD(0, bA);
  __syncthreads();     // tile 0 resident for all waves

  for (int tt = 0; tt < 32; tt += 2) {  // 2x unroll: bias regs ping-pong
    BODY(tt,     bA, bB);
    BODY(tt + 1, bB, bA);
  }

  // final: sum partials across the 4 lg-groups holding the same q = ll
  lsum += __shfl_xor(lsum, 16);
  lsum += __shfl_xor(lsum, 32);
  float linv = 1.0f / lsum;
#pragma unroll
  for (int df = 0; df < 4; ++df)
#pragma unroll
    for (int r = 0; r < 4; ++r) {
      size_t orow = (size_t)(b * S_ + q0 + ll) * D_ + h * 64 + df * 16 + lg * 4 + r;
      Oa[orow] = (_Float16)(accO[df][r] * linv);
    }
}

// ---------------- launcher ----------------
extern "C" void kernel_launch(void* const* d_in, const int* in_sizes, int n_in,
                              void* d_out, int out_size, void* d_ws, size_t ws_size,
                              hipStream_t stream) {
  const float* q    = (const float*)d_in[0];
  const float* k    = (const float*)d_in[1];
  const float* v    = (const float*)d_in[2];
  const float* td   = (const float*)d_in[3];
  const int*   mask = (const int*)d_in[4];
  const float* Wq   = (const float*)d_in[5];
  const float* bq   = (const float*)d_in[6];
  const float* Wk   = (const float*)d_in[7];
  const float* bk   = (const float*)d_in[8];
  const float* Wv   = (const float*)d_in[9];
  const float* bv   = (const float*)d_in[10];
  const float* Wo   = (const float*)d_in[11];
  const float* bo   = (const float*)d_in[12];
  const float* gm   = (const float*)d_in[13];

  const size_t MD = (size_t)M_ * D_;      // 8388608
  const size_t WW = (size_t)D_ * D_;      // 1048576
  if (ws_size < (8 * MD + 4 * WW) * sizeof(_Float16)) return;

  _Float16* base = (_Float16*)d_ws;
  _Float16* qh = base;
  _Float16* kh = qh + MD;
  _Float16* vh = kh + MD;
  _Float16* wq = vh + MD;
  _Float16* wk = wq + WW;
  _Float16* wv = wk + WW;
  _Float16* wo = wv + WW;
  _Float16* Qp = wo + WW;
  _Float16* Kp = Qp + MD;
  _Float16* Vp = Kp + MD;     // unused (V written transposed directly)
  _Float16* Vt = Vp + MD;
  _Float16* Oa = Vt + MD;
  _Float16* biasN = qh;   // reuse qh+kh (2*MD = B*S*S) after gemmQ/gemmK consume them

  CastArgs ca;
  ca.src[0] = q;  ca.src[1] = k;  ca.src[2] = v;
  ca.src[3] = Wq; ca.src[4] = Wk; ca.src[5] = Wv; ca.src[6] = Wo;
  ca.dst[0] = qh; ca.dst[1] = kh; ca.dst[2] = vh;
  ca.dst[3] = wq; ca.dst[4] = wk; ca.dst[5] = wv; ca.dst[6] = wo;
  int sizes[7] = {(int)(MD / 8), (int)(MD / 8), (int)(MD / 8),
                  (int)(WW / 8), (int)(WW / 8), (int)(WW / 8), (int)(WW / 8)};
  int c = 0; ca.cum[0] = 0;
  for (int i = 0; i < 7; ++i) { c += sizes[i]; ca.cum[i + 1] = c; }
  cast_kernel<<<(c + 255) / 256, 256, 0, stream>>>(ca);

  dim3 gg(64, 8);
  // Q scale = (1/sqrt(64)) * (1/ln2) so softmax exp becomes a bare v_exp_f32 (2^x)
  gemm_bt<0><<<gg, 256, 0, stream>>>(qh, wq, bq, Qp, 0.18033688011112042f);
  gemm_bt<0><<<gg, 256, 0, stream>>>(kh, wk, bk, Kp, 1.0f);
  bias_kernel<<<8192, 256, 0, stream>>>(td, mask, gm, biasN);      // overwrites qh/kh
  gemm_bt<2><<<gg, 256, 0, stream>>>(vh, wv, bv, Vt, 1.0f);        // fused transpose
  attn_kernel<<<2048, 256, 0, stream>>>(Qp, Kp, Vt, biasN, Oa);
  gemm_bt<1><<<gg, 256, 0, stream>>>(Oa, wo, bo, d_out, 1.0f);
}